// Round 1
// 856.987 us; speedup vs baseline: 3.1096x; 3.1096x over previous
//
#include <hip/hip_runtime.h>
#include <hip/hip_bf16.h>
#include <initializer_list>

typedef _Float16 half8 __attribute__((ext_vector_type(8)));
typedef float floatx4 __attribute__((ext_vector_type(4)));

#define MFMA16(a, b, c) __builtin_amdgcn_mfma_f32_16x16x32_f16((a), (b), (c), 0, 0, 0)

// ---------------------------------------------------------------- LayerNorm
// one block (256 threads) per row of 512; fp32 in, fp32 math, fp16 out
__global__ __launch_bounds__(256) void ln_kernel(const float* __restrict__ x,
                                                 const float* __restrict__ gamma,
                                                 const float* __restrict__ beta,
                                                 _Float16* __restrict__ xn) {
    int row = blockIdx.x;
    int tid = threadIdx.x;
    float2 v = ((const float2*)(x + (size_t)row * 512))[tid];

    __shared__ float red[4];
    __shared__ float mv[2];

    float s = v.x + v.y;
#pragma unroll
    for (int o = 32; o > 0; o >>= 1) s += __shfl_down(s, o);
    if ((tid & 63) == 0) red[tid >> 6] = s;
    __syncthreads();
    if (tid == 0) mv[0] = (red[0] + red[1] + red[2] + red[3]) * (1.f / 512.f);
    __syncthreads();
    float mean = mv[0];

    float dx = v.x - mean, dy = v.y - mean;
    float sq = dx * dx + dy * dy;
#pragma unroll
    for (int o = 32; o > 0; o >>= 1) sq += __shfl_xor(sq, o);
    __syncthreads();
    if ((tid & 63) == 0) red[tid >> 6] = sq;
    __syncthreads();
    if (tid == 0) mv[1] = rsqrtf((red[0] + red[1] + red[2] + red[3]) * (1.f / 512.f) + 1e-5f);
    __syncthreads();
    float rstd = mv[1];

    float g0 = gamma[tid * 2], g1 = gamma[tid * 2 + 1];
    float b0 = beta[tid * 2], b1 = beta[tid * 2 + 1];
    union { _Float16 h[2]; unsigned int u; } pk;
    pk.h[0] = (_Float16)(dx * rstd * g0 + b0);
    pk.h[1] = (_Float16)(dy * rstd * g1 + b1);
    ((unsigned int*)(xn + (size_t)row * 512))[tid] = pk.u;
}

// ------------------------------------------------- transpose + cast fp32->fp16
__global__ void transpose_cast(const float* __restrict__ in, _Float16* __restrict__ out,
                               int R, int C) {
    int idx = blockIdx.x * 256 + threadIdx.x;
    if (idx >= R * C) return;
    int orow = idx / R;
    int ocol = idx - orow * R;
    out[idx] = (_Float16)in[(size_t)ocol * C + orow];
}

// ---------------------------------------------------------------- GEMM (B^T)
// C[M,N] = A[M,K] @ Bt[N,K]^T + bias[N]
// OUTMODE 1: fp32 store (final output)
// OUTMODE 2: QKV-split writer. N==3072, grid.y==24; each col-block of 128 is
//   either a Q|K block (by%3==0 -> qk buffer, stride 1024, layout [b*n][h*128+qk])
//   or a V block (by%3 in {1,2} -> Vt buffer, TRANSPOSED: [b][h][d][n]).
template <int OUTMODE>
__global__ __launch_bounds__(256) void gemm_bt(const _Float16* __restrict__ A,
                                               const _Float16* __restrict__ Bt,
                                               const float* __restrict__ bias,
                                               void* __restrict__ Cout,
                                               _Float16* __restrict__ Vt,
                                               int M, int N, int K) {
    __shared__ __align__(16) _Float16 Asb[128 * 40];
    __shared__ __align__(16) _Float16 Bsb[128 * 40];

    int m0 = blockIdx.x * 128;
    int n0 = blockIdx.y * 128;
    int tid = threadIdx.x;
    int w = tid >> 6, lane = tid & 63, lrow = lane & 15, quad = lane >> 4;
    int wm = (w >> 1) * 64, wn = (w & 1) * 64;

    floatx4 acc[4][4];
#pragma unroll
    for (int i = 0; i < 4; ++i)
#pragma unroll
        for (int j = 0; j < 4; ++j) acc[i][j] = (floatx4){0.f, 0.f, 0.f, 0.f};

    for (int k0 = 0; k0 < K; k0 += 32) {
        __syncthreads();
#pragma unroll
        for (int it = 0; it < 2; ++it) {
            int c = tid + it * 256;
            int rr = c >> 2;
            int c8 = (c & 3) * 8;
            uint4 ta = *(const uint4*)(A + (size_t)(m0 + rr) * K + k0 + c8);
            uint4 tb = *(const uint4*)(Bt + (size_t)(n0 + rr) * K + k0 + c8);
            *(uint4*)&Asb[rr * 40 + c8] = ta;
            *(uint4*)&Bsb[rr * 40 + c8] = tb;
        }
        __syncthreads();

        half8 af[4], bf[4];
#pragma unroll
        for (int i = 0; i < 4; ++i)
            af[i] = *(const half8*)&Asb[(wm + i * 16 + lrow) * 40 + quad * 8];
#pragma unroll
        for (int j = 0; j < 4; ++j)
            bf[j] = *(const half8*)&Bsb[(wn + j * 16 + lrow) * 40 + quad * 8];
#pragma unroll
        for (int i = 0; i < 4; ++i)
#pragma unroll
            for (int j = 0; j < 4; ++j)
                acc[i][j] = MFMA16(af[i], bf[j], acc[i][j]);
    }

    int hh = blockIdx.y / 3;
    int part = blockIdx.y - hh * 3;

#pragma unroll
    for (int i = 0; i < 4; ++i)
#pragma unroll
        for (int j = 0; j < 4; ++j) {
            int colg = n0 + wn + j * 16 + lrow;
            int coll = wn + j * 16 + lrow;  // 0..127 within col-block
            float bv = bias[colg];
#pragma unroll
            for (int r = 0; r < 4; ++r) {
                int rowg = m0 + wm + i * 16 + quad * 4 + r;
                float v = acc[i][j][r] + bv;
                if (OUTMODE == 1) {
                    ((float*)Cout)[(size_t)rowg * N + colg] = v;  // fp32 final output
                } else {
                    if (part == 0) {
                        // Q|K: compact layout [row][h*128 + (q:0..63 | k:64..127)]
                        ((_Float16*)Cout)[(size_t)rowg * 1024 + hh * 128 + coll] = (_Float16)v;
                    } else {
                        // V: write transposed [b][h][d][n]
                        int d = (part - 1) * 128 + coll;
                        int b_rel = rowg >> 10;
                        int n = rowg & 1023;
                        Vt[(((size_t)b_rel * 8 + hh) * 256 + d) * 1024 + n] = (_Float16)v;
                    }
                }
            }
        }
}

// ---------------------------------------------------------------- attention
// qk layout per (b,n): H blocks of 128 = [q 64][k 64], fp16 (stride 1024)
// vt layout: [b][h][d=256][n=1024], fp16 (V pre-transposed by the QKV GEMM)
// grid (16,8,CB) relabeled so all q-tiles of one (h,b) share an XCD.
// 4 waves x 16 q-rows. Swapped QK^T (mfma(K,Q)) -> each lane owns ONE q-row:
// softmax reduce = 2 shfl_xor; P stays in registers; V staged into LDS in
// PV-fragment key order so P needs no redistribution.
__global__ __launch_bounds__(256) void attn_kernel(const _Float16* __restrict__ qk,
                                                   const _Float16* __restrict__ vt,
                                                   const float* __restrict__ biases,
                                                   _Float16* __restrict__ out) {
    // XCD-aware relabel (bijective over (x,y)): XCD = linear%8 = blockIdx.x&7
    int h  = blockIdx.x & 7;
    int qt = (blockIdx.x >> 3) | (blockIdx.y << 1);
    int b  = blockIdx.z;

    int tid = threadIdx.x;
    int w = tid >> 6, lane = tid & 63, lrow = lane & 15, quad = lane >> 4;

    __shared__ float bias_lds[1024];
    __shared__ __align__(16) _Float16 K_lds[32 * 72];  // [key][kd] stride 72 (conflict-free)
    __shared__ __align__(16) _Float16 V_t[256 * 32];   // [d][k-slot], PV-permuted key order

    for (int i = tid; i < 1024; i += 256) bias_lds[i] = biases[h * 1024 + i];

    // ---- Q fragments (B-operand: lane row = lrow = local q) ----
    int qrow = qt * 64 + w * 16 + lrow;
    const _Float16* qbase = qk + ((size_t)(b * 1024 + qrow)) * 1024 + h * 128;
    half8 aq0 = *(const half8*)(qbase + quad * 8);
    half8 aq1 = *(const half8*)(qbase + 32 + quad * 8);

    // ---- staging addressing ----
    int key_l = tid >> 3, kd8 = (tid & 7) * 8;
    const _Float16* ksrc = qk + ((size_t)(b * 1024 + key_l)) * 1024 + h * 128 + 64 + kd8;
    int cc = tid & 3;  // key-chunk (doubles as PV quad slot)
    const _Float16* vsrc0 = vt + ((size_t)((b * 8 + h) * 256 + (tid >> 2))) * 1024 + cc * 4;

    // per-lane bias columns: k = kt*32 + t*16 + quad*4 + r -> kr == kt, kc loop-invariant
    int qr = qrow >> 5, qc = qrow & 31;
    int bcol0[4], bcol1[4];
#pragma unroll
    for (int r = 0; r < 4; ++r) {
        bcol0[r] = abs(qc - (quad * 4 + r));
        bcol1[r] = abs(qc - (16 + quad * 4 + r));
    }

    float m_r = -1e30f, l_r = 0.f;
    floatx4 od[16];
#pragma unroll
    for (int dt = 0; dt < 16; ++dt) od[dt] = (floatx4){0.f, 0.f, 0.f, 0.f};

    uint4 kreg;
    uint2 vA[4], vB[4];

    // prologue: global loads for tile 0
    kreg = *(const uint4*)ksrc;
#pragma unroll
    for (int it = 0; it < 4; ++it) {
        const _Float16* p = vsrc0 + (size_t)it * 64 * 1024;
        vA[it] = *(const uint2*)p;
        vB[it] = *(const uint2*)(p + 16);
    }

    for (int kt = 0; kt < 32; ++kt) {
        // ---- write staged tile (vector LDS stores, conflict-free) ----
        *(uint4*)&K_lds[key_l * 72 + kd8] = kreg;
#pragma unroll
        for (int it = 0; it < 4; ++it) {
            uint4 v;
            v.x = vA[it].x; v.y = vA[it].y; v.z = vB[it].x; v.w = vB[it].y;
            *(uint4*)&V_t[((tid >> 2) + it * 64) * 32 + cc * 8] = v;
        }
        __syncthreads();

        // ---- T14: early-issue next tile's global loads (hide HBM under compute) ----
        if (kt < 31) {
            kreg = *(const uint4*)(ksrc + (size_t)(kt + 1) * 32 * 1024);
            const _Float16* vp = vsrc0 + (size_t)(kt + 1) * 32;
#pragma unroll
            for (int it = 0; it < 4; ++it) {
                const _Float16* p = vp + (size_t)it * 64 * 1024;
                vA[it] = *(const uint2*)p;
                vB[it] = *(const uint2*)(p + 16);
            }
        }

        // ---- QK^T swapped: S^T[k][q]; lane (lrow,quad) reg r = S[q=lrow][k=t*16+quad*4+r]
        floatx4 sc0 = (floatx4){0.f, 0.f, 0.f, 0.f}, sc1 = sc0;
        {
            half8 kf;
            kf = *(const half8*)&K_lds[lrow * 72 + quad * 8];              sc0 = MFMA16(kf, aq0, sc0);
            kf = *(const half8*)&K_lds[lrow * 72 + 32 + quad * 8];         sc0 = MFMA16(kf, aq1, sc0);
            kf = *(const half8*)&K_lds[(16 + lrow) * 72 + quad * 8];       sc1 = MFMA16(kf, aq0, sc1);
            kf = *(const half8*)&K_lds[(16 + lrow) * 72 + 32 + quad * 8];  sc1 = MFMA16(kf, aq1, sc1);
        }

        int rowoff = abs(qr - kt) << 5;
        float s0[4], s1[4];
#pragma unroll
        for (int r = 0; r < 4; ++r) {
            s0[r] = sc0[r] * 0.125f + bias_lds[rowoff + bcol0[r]];
            s1[r] = sc1[r] * 0.125f + bias_lds[rowoff + bcol1[r]];
        }

        float pmax = fmaxf(fmaxf(fmaxf(s0[0], s0[1]), fmaxf(s0[2], s0[3])),
                           fmaxf(fmaxf(s1[0], s1[1]), fmaxf(s1[2], s1[3])));
        pmax = fmaxf(pmax, __shfl_xor(pmax, 16));
        pmax = fmaxf(pmax, __shfl_xor(pmax, 32));

        // T13 defer-max: rescale only when the running max grows by >8 (rare)
        if (!__all(pmax - m_r <= 8.f)) {
            float mnew = fmaxf(m_r, pmax);
            float alpha = __expf(m_r - mnew);
            m_r = mnew;
            l_r *= alpha;
            float a4[4];
#pragma unroll
            for (int r = 0; r < 4; ++r) a4[r] = __shfl(alpha, quad * 4 + r, 16);
#pragma unroll
            for (int dt = 0; dt < 16; ++dt)
#pragma unroll
                for (int r = 0; r < 4; ++r) od[dt][r] *= a4[r];
        }

        float p0[4], p1[4], rs = 0.f;
#pragma unroll
        for (int r = 0; r < 4; ++r) { p0[r] = __expf(s0[r] - m_r); rs += p0[r]; }
#pragma unroll
        for (int r = 0; r < 4; ++r) { p1[r] = __expf(s1[r] - m_r); rs += p1[r]; }
        rs += __shfl_xor(rs, 16);
        rs += __shfl_xor(rs, 32);
        l_r += rs;

        // pack P as the PV A-fragment: slot j = quad*8 + (t*4+r) <-> key t*16+quad*4+r,
        // which is exactly the key order V_t was staged in.
        union H8 { _Float16 h[8]; half8 v; } pa;
#pragma unroll
        for (int r = 0; r < 4; ++r) { pa.h[r] = (_Float16)p0[r]; pa.h[4 + r] = (_Float16)p1[r]; }

#pragma unroll
        for (int dt = 0; dt < 16; ++dt) {
            half8 bv = *(const half8*)&V_t[(dt * 16 + lrow) * 32 + quad * 8];
            od[dt] = MFMA16(pa.v, bv, od[dt]);
        }
        __syncthreads();
    }

    // epilogue: od rows live in quad*4+r space; l lives in lrow space -> shfl
#pragma unroll
    for (int r = 0; r < 4; ++r) {
        float lq = __shfl(l_r, quad * 4 + r, 16);
        float inv = 1.f / lq;
        int qg = qt * 64 + w * 16 + quad * 4 + r;
        _Float16* orow = out + ((size_t)(b * 1024 + qg)) * 2048 + h * 256;
#pragma unroll
        for (int dt = 0; dt < 16; ++dt)
            orow[dt * 16 + lrow] = (_Float16)(od[dt][r] * inv);
    }
}

// ---------------------------------------------------------------- launch
extern "C" void kernel_launch(void* const* d_in, const int* in_sizes, int n_in,
                              void* d_out, int out_size, void* d_ws, size_t ws_size,
                              hipStream_t stream) {
    const float* x      = (const float*)d_in[0];
    const float* gamma  = (const float*)d_in[1];
    const float* beta   = (const float*)d_in[2];
    const float* qkv_w  = (const float*)d_in[3];
    const float* qkv_b  = (const float*)d_in[4];
    const float* proj_w = (const float*)d_in[5];
    const float* proj_b = (const float*)d_in[6];
    const float* biases = (const float*)d_in[7];
    // d_in[8] = bias_idxs: computed analytically in-kernel

    float* out = (float*)d_out;  // fp32 final output

    _Float16* ws      = (_Float16*)d_ws;
    _Float16* qkv_wt  = ws;                                   //  512*3072
    _Float16* proj_wt = qkv_wt + (size_t)512 * 3072;          // 2048*512
    _Float16* xn      = proj_wt + (size_t)2048 * 512;         // 32768*512
    _Float16* chunk0  = xn + (size_t)32768 * 512;

    const size_t FIXED_HALVES = (size_t)512 * 3072 + (size_t)2048 * 512 + (size_t)32768 * 512;
    int CB = 0;
    for (int cb : {16, 8, 4, 2, 1}) {
        // per-chunk: qk (1024) + vt (2048) + att (2048) halves per (b,n) row
        size_t halves = FIXED_HALVES + (size_t)cb * 1024 * (1024 + 2048 + 2048);
        if (halves * sizeof(_Float16) <= ws_size) { CB = cb; break; }
    }
    if (CB == 0) return;
    _Float16* qk_c  = chunk0;                                 // CB*1024*1024
    _Float16* vt_c  = qk_c + (size_t)CB * 1024 * 1024;        // CB*1024*2048  [b][h][d][n]
    _Float16* att_c = vt_c + (size_t)CB * 1024 * 2048;        // CB*1024*2048

    transpose_cast<<<(512 * 3072 + 255) / 256, 256, 0, stream>>>(qkv_w, qkv_wt, 512, 3072);
    transpose_cast<<<(2048 * 512 + 255) / 256, 256, 0, stream>>>(proj_w, proj_wt, 2048, 512);
    ln_kernel<<<32768, 256, 0, stream>>>(x, gamma, beta, xn);

    const int MC = CB * 1024;
    for (int c = 0; c < 32 / CB; ++c) {
        const _Float16* xn_c = xn + (size_t)c * MC * 512;
        gemm_bt<2><<<dim3(MC / 128, 24), 256, 0, stream>>>(xn_c, qkv_wt, qkv_b,
                                                           (void*)qk_c, vt_c, MC, 3072, 512);
        attn_kernel<<<dim3(16, 8, CB), 256, 0, stream>>>(qk_c, vt_c, biases, att_c);
        float* out_c = out + (size_t)c * MC * 512;
        gemm_bt<1><<<dim3(MC / 128, 4), 256, 0, stream>>>(att_c, proj_wt, proj_b,
                                                          (void*)out_c, nullptr, MC, 512, 2048);
    }
}